// Round 3
// baseline (18352.521 us; speedup 1.0000x reference)
//
#include <hip/hip_runtime.h>
#include <hip/hip_bf16.h>

#define HD   1024
#define GD   4096   // 4*H
#define TT   4096
#define NWG  256

// ---------------------------------------------------------------- embed
__global__ void embed_kernel(const int* __restrict__ tokens,
                             const float* __restrict__ emb,
                             float* __restrict__ X) {
    int t = blockIdx.x;
    int tok = tokens[t];
    const float4* src = reinterpret_cast<const float4*>(emb + (size_t)tok * HD);
    float4* dst = reinterpret_cast<float4*>(X + (size_t)t * HD);
    dst[threadIdx.x] = src[threadIdx.x];
}

// ---------------------------------------------------------------- gx GEMM
// gx[t][n] = sum_k X[t][k] * Wih[n][k] + bih[n] + bhh[n]
#define BM 128
#define BN 128
#define BK 16
#define LDP 132

__global__ __launch_bounds__(256, 2) void gemm_gx(
    const float* __restrict__ X,      // TT x HD
    const float* __restrict__ Wih,    // GD x HD
    const float* __restrict__ bih,
    const float* __restrict__ bhh,
    float* __restrict__ gxout)        // TT x GD
{
    __shared__ float As[BK][LDP];
    __shared__ float Bs[BK][LDP];
    const int tid = threadIdx.x;
    const int m0 = blockIdx.x * BM;
    const int n0 = blockIdx.y * BN;
    const int tx = tid & 15;
    const int ty = tid >> 4;

    float acc[8][8] = {};

    for (int kt = 0; kt < HD; kt += BK) {
#pragma unroll
        for (int p = 0; p < 2; ++p) {
            int e = p * 256 + tid;           // 0..511 float4 slots
            int row = e >> 2;
            int quad = e & 3;
            float4 av = *reinterpret_cast<const float4*>(
                &X[(size_t)(m0 + row) * HD + kt + quad * 4]);
            float4 bv = *reinterpret_cast<const float4*>(
                &Wih[(size_t)(n0 + row) * HD + kt + quad * 4]);
            As[quad * 4 + 0][row] = av.x;
            As[quad * 4 + 1][row] = av.y;
            As[quad * 4 + 2][row] = av.z;
            As[quad * 4 + 3][row] = av.w;
            Bs[quad * 4 + 0][row] = bv.x;
            Bs[quad * 4 + 1][row] = bv.y;
            Bs[quad * 4 + 2][row] = bv.z;
            Bs[quad * 4 + 3][row] = bv.w;
        }
        __syncthreads();
#pragma unroll
        for (int k = 0; k < BK; ++k) {
            float4 a0 = *reinterpret_cast<const float4*>(&As[k][ty * 8]);
            float4 a1 = *reinterpret_cast<const float4*>(&As[k][ty * 8 + 4]);
            float4 b0 = *reinterpret_cast<const float4*>(&Bs[k][tx * 8]);
            float4 b1 = *reinterpret_cast<const float4*>(&Bs[k][tx * 8 + 4]);
            float a[8] = {a0.x, a0.y, a0.z, a0.w, a1.x, a1.y, a1.z, a1.w};
            float b[8] = {b0.x, b0.y, b0.z, b0.w, b1.x, b1.y, b1.z, b1.w};
#pragma unroll
            for (int i = 0; i < 8; ++i)
#pragma unroll
                for (int j = 0; j < 8; ++j)
                    acc[i][j] += a[i] * b[j];
        }
        __syncthreads();
    }

    float bias[8];
#pragma unroll
    for (int j = 0; j < 8; ++j) {
        int n = n0 + tx * 8 + j;
        bias[j] = bih[n] + bhh[n];
    }
#pragma unroll
    for (int i = 0; i < 8; ++i) {
        size_t o = (size_t)(m0 + ty * 8 + i) * GD + n0 + tx * 8;
        float4 s0 = {acc[i][0] + bias[0], acc[i][1] + bias[1],
                     acc[i][2] + bias[2], acc[i][3] + bias[3]};
        float4 s1 = {acc[i][4] + bias[4], acc[i][5] + bias[5],
                     acc[i][6] + bias[6], acc[i][7] + bias[7]};
        *reinterpret_cast<float4*>(&gxout[o]) = s0;
        *reinterpret_cast<float4*>(&gxout[o + 4]) = s1;
    }
}

// ---------------------------------------------------------------- LSTM scan
// 256 WGs x 256 threads (4 waves). Wave w of WG b owns h element j = b*4+w,
// computing all four gates (lane = gate*16 + chunk). Weight columns per
// thread are {chunk*4 + 64q + e} -> conflict-free float4 LDS reads.
// Cross-WG h broadcast: tagged u64 mailboxes (ping-pong by step parity),
// polled with branch-free parallel atomic loads (4 in flight per thread).
__device__ __forceinline__ float sigmoid_(float x) {
    return 1.f / (1.f + __expf(-x));
}
__device__ __forceinline__ float tanh_(float x) {
    return __builtin_fmaf(2.f, 1.f / (1.f + __expf(-2.f * x)), -1.f);
}
__device__ __forceinline__ float bcast_(float v, int l) {
    return __uint_as_float(__builtin_amdgcn_readlane(__float_as_uint(v), l));
}

__global__ __launch_bounds__(256, 1) void lstm_scan(
    const float* __restrict__ gx,                 // TT x GD (includes biases)
    const float* __restrict__ whh,                // GD x HD
    float* __restrict__ out,                      // TT*HD + HD + HD
    unsigned long long* __restrict__ hbuf)        // 2 x HD
{
    const int tid   = threadIdx.x;
    const int b     = blockIdx.x;
    const int lane  = tid & 63;
    const int wv    = tid >> 6;          // wave id == jj
    const int chunk = lane & 15;         // col chunk
    const int gate  = lane >> 4;         // 0..3 (i,f,g,o)
    const int j     = b * 4 + wv;        // owned h element
    const int R     = gate * HD + j;     // weight row for this lane

    // weights -> registers (interleaved column layout)
    float w[64];
    {
        const float* wrow = whh + (size_t)R * HD;
#pragma unroll
        for (int q = 0; q < 16; ++q) {
            float4 v = *reinterpret_cast<const float4*>(&wrow[chunk * 4 + q * 64]);
            w[q * 4 + 0] = v.x; w[q * 4 + 1] = v.y;
            w[q * 4 + 2] = v.z; w[q * 4 + 3] = v.w;
        }
    }

    __shared__ float h_lds[2][HD];
#pragma unroll
    for (int q = 0; q < 4; ++q) h_lds[0][tid * 4 + q] = 0.f;   // h(0) = 0
    __syncthreads();

    float c_reg = 0.f;
    float gx_cur = gx[R];                // step 1 value

    // both parity mailbox bases for this thread's polled slice
    unsigned long long* const mb[2] = { &hbuf[tid * 4], &hbuf[HD + tid * 4] };

    for (int s = 1; s <= TT; ++s) {
        const int cb = (s - 1) & 1;      // buffer holding h(s-1)
        const int nb = s & 1;            // buffer for h(s)

        // prefetch next step's gx (consumed next iteration)
        float gx_nxt = 0.f;
        if (s < TT) gx_nxt = gx[(size_t)s * GD + R];

        // dot product over h(s-1): 64 FMA per lane, conflict-free LDS reads
        float acc = (chunk == 0) ? gx_cur : 0.f;
        {
            const float* hb = h_lds[cb];
#pragma unroll
            for (int q = 0; q < 16; ++q) {
                float4 hv = *reinterpret_cast<const float4*>(&hb[chunk * 4 + q * 64]);
                acc = __builtin_fmaf(w[q * 4 + 0], hv.x, acc);
                acc = __builtin_fmaf(w[q * 4 + 1], hv.y, acc);
                acc = __builtin_fmaf(w[q * 4 + 2], hv.z, acc);
                acc = __builtin_fmaf(w[q * 4 + 3], hv.w, acc);
            }
        }
        // reduce within each 16-lane gate group
        acc += __shfl_xor(acc, 1, 64);
        acc += __shfl_xor(acc, 2, 64);
        acc += __shfl_xor(acc, 4, 64);
        acc += __shfl_xor(acc, 8, 64);
        // broadcast the four gate sums to every lane (SGPR path, off LDS pipe)
        float si = bcast_(acc, 0);
        float sf = bcast_(acc, 16);
        float sg = bcast_(acc, 32);
        float so = bcast_(acc, 48);

        // gate math, wave-uniform (replicated in all 64 lanes)
        float ii = sigmoid_(si);
        float ff = sigmoid_(sf);
        float gg = tanh_(sg);
        float oo = sigmoid_(so);
        c_reg = __builtin_fmaf(ff, c_reg, ii * gg);
        float hh = oo * tanh_(c_reg);

        if (lane == 0) {
            // publish first (critical path for all other WGs)
            unsigned long long pkt =
                ((unsigned long long)(unsigned)s << 32) | __float_as_uint(hh);
            __hip_atomic_store(&hbuf[(size_t)nb * HD + j], pkt,
                               __ATOMIC_RELAXED, __HIP_MEMORY_SCOPE_AGENT);
            h_lds[nb][j] = hh;                          // own value, LDS path
            out[(size_t)(s - 1) * HD + j] = hh;         // hs output
            if (s == TT) {
                out[(size_t)TT * HD + j] = hh;          // h_n
                out[(size_t)TT * HD + HD + j] = c_reg;  // c_n
            }
        }
        gx_cur = gx_nxt;

        // gather h(s) from other WGs: thread t owns WG t's 4 words.
        // Branch-free poll: all 4 loads issued unconditionally (in flight
        // together), single fused tag check.
        if (s < TT) {
            if (tid != b) {
                unsigned long long* src = mb[nb];
                const unsigned long long tag = (unsigned long long)(unsigned)s;
                unsigned long long v0, v1, v2, v3;
                int guard = 0;
                for (;;) {
                    v0 = __hip_atomic_load(&src[0], __ATOMIC_RELAXED,
                                           __HIP_MEMORY_SCOPE_AGENT);
                    v1 = __hip_atomic_load(&src[1], __ATOMIC_RELAXED,
                                           __HIP_MEMORY_SCOPE_AGENT);
                    v2 = __hip_atomic_load(&src[2], __ATOMIC_RELAXED,
                                           __HIP_MEMORY_SCOPE_AGENT);
                    v3 = __hip_atomic_load(&src[3], __ATOMIC_RELAXED,
                                           __HIP_MEMORY_SCOPE_AGENT);
                    bool ok = ((v0 >> 32) == tag) & ((v1 >> 32) == tag) &
                              ((v2 >> 32) == tag) & ((v3 >> 32) == tag);
                    if (ok) break;
                    if (++guard > 4096) {                // never expected
                        if (guard > (1 << 18)) break;
                        __builtin_amdgcn_s_sleep(1);
                    }
                }
                float4 hv;
                hv.x = __uint_as_float((unsigned int)v0);
                hv.y = __uint_as_float((unsigned int)v1);
                hv.z = __uint_as_float((unsigned int)v2);
                hv.w = __uint_as_float((unsigned int)v3);
                *reinterpret_cast<float4*>(&h_lds[nb][tid * 4]) = hv;
            }
            __syncthreads();
        }
    }
}

// ---------------------------------------------------------------- launch
extern "C" void kernel_launch(void* const* d_in, const int* in_sizes, int n_in,
                              void* d_out, int out_size, void* d_ws, size_t ws_size,
                              hipStream_t stream) {
    const int*   tokens = (const int*)d_in[0];
    const float* emb    = (const float*)d_in[1];
    const float* w_ih   = (const float*)d_in[2];
    const float* w_hh   = (const float*)d_in[3];
    const float* b_ih   = (const float*)d_in[4];
    const float* b_hh   = (const float*)d_in[5];
    float* out = (float*)d_out;

    char* ws = (char*)d_ws;
    unsigned long long* hbuf = (unsigned long long*)ws;              // 16 KB
    float* X  = (float*)(ws + (size_t)16384);                        // 16 MB
    float* gx = (float*)(ws + (size_t)16384 + (size_t)TT * HD * 4);  // 64 MB

    hipMemsetAsync(hbuf, 0, 2 * HD * sizeof(unsigned long long), stream);
    embed_kernel<<<TT, 256, 0, stream>>>(tokens, emb, X);
    gemm_gx<<<dim3(TT / BM, GD / BN), 256, 0, stream>>>(X, w_ih, b_ih, b_hh, gx);
    lstm_scan<<<NWG, 256, 0, stream>>>(gx, w_hh, out, hbuf);
}

// Round 4
// 16216.219 us; speedup vs baseline: 1.1317x; 1.1317x over previous
//
#include <hip/hip_runtime.h>
#include <hip/hip_bf16.h>

#define HD   1024
#define GD   4096   // 4*H
#define TT   4096
#define NWG  256
#define MBS  16     // u64 slots per mailbox entry (128 B stride)

// ---------------------------------------------------------------- gx GEMM
// gx[t][n] = sum_k emb[tokens[t]][k] * Wih[n][k] + bih[n] + bhh[n]
// (embedding gather fused into the A-tile load)
#define BM 128
#define BN 128
#define BK 16
#define LDP 132

__global__ __launch_bounds__(256, 2) void gemm_gx(
    const int* __restrict__ tokens,
    const float* __restrict__ emb,    // VOCAB x HD
    const float* __restrict__ Wih,    // GD x HD
    const float* __restrict__ bih,
    const float* __restrict__ bhh,
    float* __restrict__ gxout)        // TT x GD
{
    __shared__ float As[BK][LDP];
    __shared__ float Bs[BK][LDP];
    const int tid = threadIdx.x;
    const int m0 = blockIdx.x * BM;
    const int n0 = blockIdx.y * BN;
    const int tx = tid & 15;
    const int ty = tid >> 4;

    const int quad = tid & 3;
    const int r0   = tid >> 2;                 // rows r0 (p=0) and r0+64 (p=1)
    const int tok0 = tokens[m0 + r0];
    const int tok1 = tokens[m0 + r0 + 64];

    float acc[8][8] = {};

    for (int kt = 0; kt < HD; kt += BK) {
        float4 av0 = *reinterpret_cast<const float4*>(
            &emb[(size_t)tok0 * HD + kt + quad * 4]);
        float4 bv0 = *reinterpret_cast<const float4*>(
            &Wih[(size_t)(n0 + r0) * HD + kt + quad * 4]);
        float4 av1 = *reinterpret_cast<const float4*>(
            &emb[(size_t)tok1 * HD + kt + quad * 4]);
        float4 bv1 = *reinterpret_cast<const float4*>(
            &Wih[(size_t)(n0 + r0 + 64) * HD + kt + quad * 4]);
        As[quad * 4 + 0][r0] = av0.x;
        As[quad * 4 + 1][r0] = av0.y;
        As[quad * 4 + 2][r0] = av0.z;
        As[quad * 4 + 3][r0] = av0.w;
        Bs[quad * 4 + 0][r0] = bv0.x;
        Bs[quad * 4 + 1][r0] = bv0.y;
        Bs[quad * 4 + 2][r0] = bv0.z;
        Bs[quad * 4 + 3][r0] = bv0.w;
        As[quad * 4 + 0][r0 + 64] = av1.x;
        As[quad * 4 + 1][r0 + 64] = av1.y;
        As[quad * 4 + 2][r0 + 64] = av1.z;
        As[quad * 4 + 3][r0 + 64] = av1.w;
        Bs[quad * 4 + 0][r0 + 64] = bv1.x;
        Bs[quad * 4 + 1][r0 + 64] = bv1.y;
        Bs[quad * 4 + 2][r0 + 64] = bv1.z;
        Bs[quad * 4 + 3][r0 + 64] = bv1.w;
        __syncthreads();
#pragma unroll
        for (int k = 0; k < BK; ++k) {
            float4 a0 = *reinterpret_cast<const float4*>(&As[k][ty * 8]);
            float4 a1 = *reinterpret_cast<const float4*>(&As[k][ty * 8 + 4]);
            float4 b0 = *reinterpret_cast<const float4*>(&Bs[k][tx * 8]);
            float4 b1 = *reinterpret_cast<const float4*>(&Bs[k][tx * 8 + 4]);
            float a[8] = {a0.x, a0.y, a0.z, a0.w, a1.x, a1.y, a1.z, a1.w};
            float b[8] = {b0.x, b0.y, b0.z, b0.w, b1.x, b1.y, b1.z, b1.w};
#pragma unroll
            for (int i = 0; i < 8; ++i)
#pragma unroll
                for (int j = 0; j < 8; ++j)
                    acc[i][j] += a[i] * b[j];
        }
        __syncthreads();
    }

    float bias[8];
#pragma unroll
    for (int j = 0; j < 8; ++j) {
        int n = n0 + tx * 8 + j;
        bias[j] = bih[n] + bhh[n];
    }
#pragma unroll
    for (int i = 0; i < 8; ++i) {
        size_t o = (size_t)(m0 + ty * 8 + i) * GD + n0 + tx * 8;
        float4 s0 = {acc[i][0] + bias[0], acc[i][1] + bias[1],
                     acc[i][2] + bias[2], acc[i][3] + bias[3]};
        float4 s1 = {acc[i][4] + bias[4], acc[i][5] + bias[5],
                     acc[i][6] + bias[6], acc[i][7] + bias[7]};
        *reinterpret_cast<float4*>(&gxout[o]) = s0;
        *reinterpret_cast<float4*>(&gxout[o + 4]) = s1;
    }
}

// ---------------------------------------------------------------- LSTM scan
// 256 WGs x 256 threads (4 waves). Wave w of WG b owns h element j = b*4+w,
// computing all four gates (lane = gate*16 + chunk). Weight columns per
// thread are {chunk*4 + 64q + e} -> conflict-free float4 LDS reads.
// Cross-WG h broadcast: tagged u64 mailboxes at 128B stride (L3-slice
// spread), ping-pong by step parity, polled with 4 parallel atomic loads +
// s_sleep rate limit. Barrier = lgkmcnt-only (global ops float across steps).
__device__ __forceinline__ float sigmoid_(float x) {
    return 1.f / (1.f + __expf(-x));
}
__device__ __forceinline__ float tanh_(float x) {
    return __builtin_fmaf(2.f, 1.f / (1.f + __expf(-2.f * x)), -1.f);
}
__device__ __forceinline__ float bcast_(float v, int l) {
    return __uint_as_float(__builtin_amdgcn_readlane(__float_as_uint(v), l));
}
__device__ __forceinline__ void lds_barrier_() {
    asm volatile("s_waitcnt lgkmcnt(0)" ::: "memory");
    __builtin_amdgcn_s_barrier();
}

__global__ __launch_bounds__(256, 1) void lstm_scan(
    const float* __restrict__ gx,                 // TT x GD (includes biases)
    const float* __restrict__ whh,                // GD x HD
    float* __restrict__ out,                      // TT*HD + HD + HD
    unsigned long long* __restrict__ hbuf)        // 2 x HD x MBS
{
    const int tid   = threadIdx.x;
    const int b     = blockIdx.x;
    const int lane  = tid & 63;
    const int wv    = tid >> 6;          // wave id == jj
    const int chunk = lane & 15;         // col chunk
    const int gate  = lane >> 4;         // 0..3 (i,f,g,o)
    const int j     = b * 4 + wv;        // owned h element
    const int R     = gate * HD + j;     // weight row for this lane

    // weights -> registers (interleaved column layout)
    float w[64];
    {
        const float* wrow = whh + (size_t)R * HD;
#pragma unroll
        for (int q = 0; q < 16; ++q) {
            float4 v = *reinterpret_cast<const float4*>(&wrow[chunk * 4 + q * 64]);
            w[q * 4 + 0] = v.x; w[q * 4 + 1] = v.y;
            w[q * 4 + 2] = v.z; w[q * 4 + 3] = v.w;
        }
    }

    __shared__ float h_lds[2][HD];
#pragma unroll
    for (int q = 0; q < 4; ++q) h_lds[0][tid * 4 + q] = 0.f;   // h(0) = 0
    lds_barrier_();

    float c_reg = 0.f;
    float gx_cur = gx[R];                // step 1 value

    // poll bases (this thread's 4 entries, each 128B apart), both parities
    unsigned long long* const mp0 = hbuf + (size_t)(tid * 4) * MBS;
    unsigned long long* const mp1 = hbuf + (size_t)(HD + tid * 4) * MBS;

    for (int s = 1; s <= TT; ++s) {
        const int cb = (s - 1) & 1;      // buffer holding h(s-1)
        const int nb = s & 1;            // buffer for h(s)

        // prefetch next step's gx (consumed next iteration; floats across
        // the barrier since we never drain vmcnt)
        float gx_nxt = 0.f;
        if (s < TT) gx_nxt = gx[(size_t)s * GD + R];

        // dot product over h(s-1): 4 independent FMA chains
        float A0 = (chunk == 0) ? gx_cur : 0.f;
        float A1 = 0.f, A2 = 0.f, A3 = 0.f;
        {
            const float* hb = h_lds[cb];
#pragma unroll
            for (int q = 0; q < 4; ++q) {
                float4 h0 = *reinterpret_cast<const float4*>(&hb[chunk * 4 + (4 * q + 0) * 64]);
                float4 h1 = *reinterpret_cast<const float4*>(&hb[chunk * 4 + (4 * q + 1) * 64]);
                float4 h2 = *reinterpret_cast<const float4*>(&hb[chunk * 4 + (4 * q + 2) * 64]);
                float4 h3 = *reinterpret_cast<const float4*>(&hb[chunk * 4 + (4 * q + 3) * 64]);
                A0 = __builtin_fmaf(w[(4 * q + 0) * 4 + 0], h0.x, A0);
                A0 = __builtin_fmaf(w[(4 * q + 0) * 4 + 1], h0.y, A0);
                A0 = __builtin_fmaf(w[(4 * q + 0) * 4 + 2], h0.z, A0);
                A0 = __builtin_fmaf(w[(4 * q + 0) * 4 + 3], h0.w, A0);
                A1 = __builtin_fmaf(w[(4 * q + 1) * 4 + 0], h1.x, A1);
                A1 = __builtin_fmaf(w[(4 * q + 1) * 4 + 1], h1.y, A1);
                A1 = __builtin_fmaf(w[(4 * q + 1) * 4 + 2], h1.z, A1);
                A1 = __builtin_fmaf(w[(4 * q + 1) * 4 + 3], h1.w, A1);
                A2 = __builtin_fmaf(w[(4 * q + 2) * 4 + 0], h2.x, A2);
                A2 = __builtin_fmaf(w[(4 * q + 2) * 4 + 1], h2.y, A2);
                A2 = __builtin_fmaf(w[(4 * q + 2) * 4 + 2], h2.z, A2);
                A2 = __builtin_fmaf(w[(4 * q + 2) * 4 + 3], h2.w, A2);
                A3 = __builtin_fmaf(w[(4 * q + 3) * 4 + 0], h3.x, A3);
                A3 = __builtin_fmaf(w[(4 * q + 3) * 4 + 1], h3.y, A3);
                A3 = __builtin_fmaf(w[(4 * q + 3) * 4 + 2], h3.z, A3);
                A3 = __builtin_fmaf(w[(4 * q + 3) * 4 + 3], h3.w, A3);
            }
        }
        float acc = (A0 + A1) + (A2 + A3);
        // reduce within each 16-lane gate group
        acc += __shfl_xor(acc, 1, 64);
        acc += __shfl_xor(acc, 2, 64);
        acc += __shfl_xor(acc, 4, 64);
        acc += __shfl_xor(acc, 8, 64);
        // broadcast the four gate sums to every lane (SGPR path)
        float si = bcast_(acc, 0);
        float sf = bcast_(acc, 16);
        float sg = bcast_(acc, 32);
        float so = bcast_(acc, 48);

        // gate math, wave-uniform (replicated in all 64 lanes)
        float ii = sigmoid_(si);
        float ff = sigmoid_(sf);
        float gg = tanh_(sg);
        float oo = sigmoid_(so);
        c_reg = __builtin_fmaf(ff, c_reg, ii * gg);
        float hh = oo * tanh_(c_reg);

        if (s < TT) {
            // publish first (critical path for all other WGs)
            if (lane == 0) {
                unsigned long long pkt =
                    ((unsigned long long)(unsigned)s << 32) | __float_as_uint(hh);
                __hip_atomic_store(&hbuf[(size_t)(nb * HD + j) * MBS], pkt,
                                   __ATOMIC_RELAXED, __HIP_MEMORY_SCOPE_AGENT);
            }
            gx_cur = gx_nxt;

            // gather h(s) from other WGs: thread t owns WG t's 4 entries
            if (tid != b) {
                unsigned long long* src = nb ? mp1 : mp0;
                const unsigned long long tg = (unsigned long long)(unsigned)s;
                unsigned long long v0, v1, v2, v3;
                int r = 0;
                for (;;) {
                    v0 = __hip_atomic_load(&src[0 * MBS], __ATOMIC_RELAXED,
                                           __HIP_MEMORY_SCOPE_AGENT);
                    v1 = __hip_atomic_load(&src[1 * MBS], __ATOMIC_RELAXED,
                                           __HIP_MEMORY_SCOPE_AGENT);
                    v2 = __hip_atomic_load(&src[2 * MBS], __ATOMIC_RELAXED,
                                           __HIP_MEMORY_SCOPE_AGENT);
                    v3 = __hip_atomic_load(&src[3 * MBS], __ATOMIC_RELAXED,
                                           __HIP_MEMORY_SCOPE_AGENT);
                    unsigned long long bad = ((v0 >> 32) ^ tg) | ((v1 >> 32) ^ tg) |
                                             ((v2 >> 32) ^ tg) | ((v3 >> 32) ^ tg);
                    if (!bad) break;
                    ++r;
                    if (r > (1 << 17)) break;          // safety: never expected
                    if (r >= 2) __builtin_amdgcn_s_sleep(1);
                }
                float4 hv;
                hv.x = __uint_as_float((unsigned int)v0);
                hv.y = __uint_as_float((unsigned int)v1);
                hv.z = __uint_as_float((unsigned int)v2);
                hv.w = __uint_as_float((unsigned int)v3);
                *reinterpret_cast<float4*>(&h_lds[nb][tid * 4]) = hv;
            }
            if (lane == 0) {
                h_lds[nb][j] = hh;                     // own value, LDS path
                out[(size_t)(s - 1) * HD + j] = hh;    // hs output (floats)
            }
            lds_barrier_();
        } else {
            if (lane == 0) {
                out[(size_t)(s - 1) * HD + j] = hh;
                out[(size_t)TT * HD + j] = hh;          // h_n
                out[(size_t)TT * HD + HD + j] = c_reg;  // c_n
            }
        }
    }
}

// ---------------------------------------------------------------- launch
extern "C" void kernel_launch(void* const* d_in, const int* in_sizes, int n_in,
                              void* d_out, int out_size, void* d_ws, size_t ws_size,
                              hipStream_t stream) {
    const int*   tokens = (const int*)d_in[0];
    const float* emb    = (const float*)d_in[1];
    const float* w_ih   = (const float*)d_in[2];
    const float* w_hh   = (const float*)d_in[3];
    const float* b_ih   = (const float*)d_in[4];
    const float* b_hh   = (const float*)d_in[5];
    float* out = (float*)d_out;

    char* ws = (char*)d_ws;
    const size_t HBUF_BYTES = (size_t)2 * HD * MBS * 8;   // 256 KB
    unsigned long long* hbuf = (unsigned long long*)ws;
    float* gx = (float*)(ws + HBUF_BYTES);                 // 64 MB

    hipMemsetAsync(hbuf, 0, HBUF_BYTES, stream);
    gemm_gx<<<dim3(TT / BM, GD / BN), 256, 0, stream>>>(tokens, emb, w_ih,
                                                        b_ih, b_hh, gx);
    lstm_scan<<<NWG, 256, 0, stream>>>(gx, w_hh, out, hbuf);
}